// Round 1
// baseline (90.438 us; speedup 1.0000x reference)
//
#include <hip/hip_runtime.h>
#include <math.h>

#define H_IN  1024
#define W_IN  1024
#define HW_IN (H_IN * W_IN)
#define H_OUT 768
#define W_OUT 768
#define HW_OUT (H_OUT * W_OUT)

struct KC {
    float sig1, inv, slope, two_over_c, half_c, quarter_c, half_over_sig1;
    float a2, a0, m_in_root;
};

__device__ __forceinline__ float inv_sigmoid(float q, const KC k) {
    if (q <= 0.f) return q * k.inv;
    if (q >= 1.f) return q * k.inv + (1.f - k.inv);
    float ssq = 2.f * k.sig1 * q - k.sig1;
    ssq = fminf(fmaxf(ssq, -0.999999f), 0.999999f);
    return k.two_over_c * atanhf(ssq) + 0.5f;
}

__device__ __forceinline__ float ext_sigmoid(float q, const KC k) {
    if (q <= 0.f) return k.slope * q;
    if (q >= 1.f) return k.slope * q + (1.f - k.slope);
    return k.half_over_sig1 * tanhf(k.half_c * q - k.quarter_c) + 0.5f;
}

__device__ __forceinline__ float mitchell(float xv) {
    float ax = fabsf(xv);
    if (ax >= 2.f) return 0.f;
    float ax2 = ax * ax, ax3 = ax2 * ax;
    if (ax < 1.f) return 7.f / 6.f * ax3 - 2.f * ax2 + 8.f / 9.f;
    return -7.f / 18.f * ax3 + 2.f * ax2 - 10.f / 3.f * ax + 16.f / 9.f;
}

__device__ __forceinline__ float robidoux(float r2, const KC k) {
    if (r2 >= 4.f) return 0.f;
    float r = sqrtf(r2 + 1e-8f);
    if (r2 < 1.f) return r2 * (-3.f * r + k.a2) + k.a0;
    float t = r - 2.f;
    return (r + k.m_in_root) * t * t;
}

__global__ __launch_bounds__(256)
void sig_precompute(const float4* __restrict__ img, float4* __restrict__ sig,
                    int n4, KC k) {
    int i = blockIdx.x * 256 + threadIdx.x;
    if (i >= n4) return;
    float4 v = img[i];
    float4 r;
    r.x = inv_sigmoid(v.x, k);
    r.y = inv_sigmoid(v.y, k);
    r.z = inv_sigmoid(v.z, k);
    r.w = inv_sigmoid(v.w, k);
    sig[i] = r;
}

template <bool PRE>
__global__ __launch_bounds__(256)
void lohalo_main(const float* __restrict__ img, const float* __restrict__ sig,
                 const float* __restrict__ grid, float* __restrict__ out, KC k) {
    const int lx = threadIdx.x & 15, ly = threadIdx.x >> 4;
    const int x = blockIdx.x * 16 + lx;
    const int y = blockIdx.y * 16 + ly;
    const int pix = y * W_OUT + x;

    // ---- Jacobian via central differences with edge clamping ----
    const float2* G = (const float2*)grid;
    float2 gc  = G[pix];
    float2 gxm = G[y * W_OUT + max(x - 1, 0)];
    float2 gxp = G[y * W_OUT + min(x + 1, W_OUT - 1)];
    float2 gym = G[max(y - 1, 0) * W_OUT + x];
    float2 gyp = G[min(y + 1, H_OUT - 1) * W_OUT + x];
    float J00 = (gxp.x - gxm.x) * 0.5f, J10 = (gxp.y - gxm.y) * 0.5f;
    float J01 = (gyp.x - gym.x) * 0.5f, J11 = (gyp.y - gym.y) * 0.5f;
    float det = J00 * J11 - J01 * J10 + 1e-8f;
    float a  = J11 / det, b = -J01 / det;
    float cI = -J10 / det, d = J00 / det;
    float n11 = a * a + b * b, n12 = a * cI + b * d, n22 = cI * cI + d * d;
    float frob = n11 + n22;
    float disc = frob * frob - 4.f / (det * det);
    float sdisc = sqrtf(fmaxf(disc, 0.f));
    float twice = frob + sdisc;
    float s1s1 = 0.5f * twice, s2s2 = 0.5f * (frob - sdisc);
    float major = sqrtf(fmaxf(s1s1, 1.f));
    float minr  = sqrtf(fmaxf(s2s2, 1.f));
    float diff1 = s1s1 - n11, diff2 = s1s1 - n22;
    bool  cnd  = diff1 * diff1 >= diff2 * diff2;
    float tu11 = cnd ? n12 : diff2;
    float tu21 = cnd ? diff1 : n12;
    float nrm = sqrtf(tu11 * tu11 + tu21 * tu21);
    float u11 = nrm > 0.f ? tu11 / nrm : 1.f;
    float u21 = nrm > 0.f ? tu21 / nrm : 0.f;
    float cMx = u11 / major, cMy = u21 / major;
    float cmx = -u21 / minr, cmy = u11 / minr;
    float theta = 1.f / (major * minr);
    bool need_ewa = twice > 2.f;

    // ---- window setup ----
    float fix = floorf(gc.x), fiy = floorf(gc.y);
    int ix = (int)fix, iy = (int)fiy;
    float fx = gc.x - (fix + 0.5f);
    float fy = gc.y - (fiy + 0.5f);

    float mx[6], my[6], rxv[6], ryv[6];
    float qx1[6], qx2[6], qy1[6], qy2[6];
    int cxi[6], cyi[6];
#pragma unroll
    for (int t = 0; t < 6; t++) {
        float o = (float)(t - 2);
        rxv[t] = fx - o;
        ryv[t] = fy - o;
        mx[t] = mitchell(rxv[t]);
        my[t] = mitchell(ryv[t]);
        qx1[t] = rxv[t] * cMx;
        qx2[t] = rxv[t] * cmx;
        qy1[t] = ryv[t] * cMy;
        qy2[t] = ryv[t] * cmy;
        cxi[t] = min(max(ix + (t - 2), 0), W_IN - 1);
        cyi[t] = min(max(iy + (t - 2), 0), H_IN - 1);
    }

    float ms0 = 0.f, ms1 = 0.f, ms2 = 0.f;

    bool any_ewa = __any(need_ewa);
    if (any_ewa) {
        float es0 = 0.f, es1 = 0.f, es2 = 0.f, tw = 0.f;
#pragma unroll
        for (int ty = 0; ty < 6; ty++) {
            const int rb = cyi[ty] * W_IN;
#pragma unroll
            for (int tx = 0; tx < 6; tx++) {
                const int off = rb + cxi[tx];
                float p0 = img[off];
                float p1 = img[off + HW_IN];
                float p2 = img[off + 2 * HW_IN];
                float s0, s1, s2;
                if constexpr (PRE) {
                    s0 = sig[off];
                    s1 = sig[off + HW_IN];
                    s2 = sig[off + 2 * HW_IN];
                } else {
                    s0 = inv_sigmoid(p0, k);
                    s1 = inv_sigmoid(p1, k);
                    s2 = inv_sigmoid(p2, k);
                }
                float wm = mx[tx] * my[ty];
                ms0 = fmaf(s0, wm, ms0);
                ms1 = fmaf(s1, wm, ms1);
                ms2 = fmaf(s2, wm, ms2);
                float q1 = qx1[tx] + qy1[ty];
                float q2 = qx2[tx] + qy2[ty];
                float r2 = q1 * q1 + q2 * q2;
                float we = robidoux(r2, k);
                tw += we;
                es0 = fmaf(p0, we, es0);
                es1 = fmaf(p1, we, es1);
                es2 = fmaf(p2, we, es2);
            }
        }
        tw += 1e-8f;
        float mv0 = ext_sigmoid(ms0, k);
        float mv1 = ext_sigmoid(ms1, k);
        float mv2 = ext_sigmoid(ms2, k);
        float ev0 = es0 / tw, ev1 = es1 / tw, ev2 = es2 / tw;
        float om = 1.f - theta;
        out[pix]              = need_ewa ? theta * mv0 + om * ev0 : mv0;
        out[HW_OUT + pix]     = need_ewa ? theta * mv1 + om * ev1 : mv1;
        out[2 * HW_OUT + pix] = need_ewa ? theta * mv2 + om * ev2 : mv2;
    } else {
#pragma unroll
        for (int ty = 0; ty < 6; ty++) {
            const int rb = cyi[ty] * W_IN;
#pragma unroll
            for (int tx = 0; tx < 6; tx++) {
                const int off = rb + cxi[tx];
                float s0, s1, s2;
                if constexpr (PRE) {
                    s0 = sig[off];
                    s1 = sig[off + HW_IN];
                    s2 = sig[off + 2 * HW_IN];
                } else {
                    s0 = inv_sigmoid(img[off], k);
                    s1 = inv_sigmoid(img[off + HW_IN], k);
                    s2 = inv_sigmoid(img[off + 2 * HW_IN], k);
                }
                float wm = mx[tx] * my[ty];
                ms0 = fmaf(s0, wm, ms0);
                ms1 = fmaf(s1, wm, ms1);
                ms2 = fmaf(s2, wm, ms2);
            }
        }
        out[pix]              = ext_sigmoid(ms0, k);
        out[HW_OUT + pix]     = ext_sigmoid(ms1, k);
        out[2 * HW_OUT + pix] = ext_sigmoid(ms2, k);
    }
}

extern "C" void kernel_launch(void* const* d_in, const int* in_sizes, int n_in,
                              void* d_out, int out_size, void* d_ws, size_t ws_size,
                              hipStream_t stream) {
    const float* img  = (const float*)d_in[0];
    const float* grid = (const float*)d_in[1];
    float* out = (float*)d_out;

    KC k;
    const double cc = 3.38589;
    const double s1 = tanh(0.25 * cc);
    const double slope = (1.0 / s1 - s1) * 0.25 * cc;
    k.sig1 = (float)s1;
    k.slope = (float)slope;
    k.inv = (float)(1.0 / slope);
    k.two_over_c = (float)(2.0 / cc);
    k.half_c = (float)(0.5 * cc);
    k.quarter_c = (float)(0.25 * cc);
    k.half_over_sig1 = (float)(0.5 / s1);
    const double sq2 = sqrt(2.0);
    k.a2 = (float)((45739.0 + 7164.0 * sq2) / 10319.0);
    k.a0 = (float)((-8926.0 - 14328.0 * sq2) / 10319.0);
    k.m_in_root = (float)((-103.0 - 36.0 * sq2) / (7.0 + 72.0 * sq2));

    dim3 grd(W_OUT / 16, H_OUT / 16);
    const size_t sig_bytes = (size_t)3 * HW_IN * sizeof(float);

    if (ws_size >= sig_bytes) {
        float* sig = (float*)d_ws;
        int n4 = 3 * HW_IN / 4;
        sig_precompute<<<(n4 + 255) / 256, 256, 0, stream>>>(
            (const float4*)img, (float4*)sig, n4, k);
        lohalo_main<true><<<grd, 256, 0, stream>>>(img, sig, grid, out, k);
    } else {
        lohalo_main<false><<<grd, 256, 0, stream>>>(img, nullptr, grid, out, k);
    }
}